// Round 2
// baseline (505.131 us; speedup 1.0000x reference)
//
#include <hip/hip_runtime.h>
#include <hip/hip_bf16.h>
#include <math.h>

typedef __attribute__((ext_vector_type(8))) short short8;
typedef __attribute__((ext_vector_type(4))) float floatx4;

__device__ inline unsigned f2bf1(float f) {
    union { float f; unsigned u; } v; v.f = f;
    return (v.u + 0x8000u) >> 16;   // round-half-up to bf16
}

__device__ inline short8 pack8(float4 a, float4 b) {
    short8 r;
    r[0] = (short)f2bf1(a.x); r[1] = (short)f2bf1(a.y);
    r[2] = (short)f2bf1(a.z); r[3] = (short)f2bf1(a.w);
    r[4] = (short)f2bf1(b.x); r[5] = (short)f2bf1(b.y);
    r[6] = (short)f2bf1(b.z); r[7] = (short)f2bf1(b.w);
    return r;
}

// -------- segment-average: x (16,128,512) -> xcf (32, 2048), m = b*16 + a ----
__global__ __launch_bounds__(128) void avg_k(const float* __restrict__ x,
                                             float* __restrict__ xcf) {
    int blk = blockIdx.x;            // a*128 + b
    int a = blk >> 7, b = blk & 127;
    int t = threadIdx.x;
    const float4 v = *(const float4*)(x + ((size_t)a * 128 + b) * 512 + t * 4);
    float s = v.x + v.y + v.z + v.w;
    s += __shfl_xor(s, 1);
    s += __shfl_xor(s, 2);
    if ((t & 3) == 0) {
        int seg = t >> 2;            // 0..31
        xcf[seg * 2048 + b * 16 + a] = s * (1.0f / 16.0f);
    }
}

// -------- thin GEMM: slab[chunk][32][N] = X[32,K-chunk] @ W[N,K-chunk]^T -----
template<int KCHUNK>
__global__ __launch_bounds__(256) void gemm_k(const float* __restrict__ X,
                                              const float* __restrict__ W,
                                              float* __restrict__ slab,
                                              int N, int K) {
    constexpr int PITCH = KCHUNK + 8;
    __shared__ unsigned short Xs[32 * PITCH];
    const int tid = threadIdx.x;
    const int bx = blockIdx.x, by = blockIdx.y;
    const int kb0 = by * KCHUNK;

    constexpr int NF4 = 32 * (KCHUNK / 4);
#pragma unroll
    for (int f = tid; f < NF4; f += 256) {
        int row = f / (KCHUNK / 4), c4 = f % (KCHUNK / 4);
        const float4 v = *(const float4*)(X + (size_t)row * K + kb0 + c4 * 4);
        ushort4 p;
        p.x = (unsigned short)f2bf1(v.x);
        p.y = (unsigned short)f2bf1(v.y);
        p.z = (unsigned short)f2bf1(v.z);
        p.w = (unsigned short)f2bf1(v.w);
        *(ushort4*)&Xs[row * PITCH + c4 * 4] = p;
    }
    __syncthreads();

    const int w = tid >> 6, lane = tid & 63;
    const int q = lane >> 4, r16 = lane & 15;
    const int nb = bx * 128 + w * 32;
    floatx4 acc[2][2] = {};
    const float* wp0 = W + (size_t)(nb + r16) * K + kb0 + q * 8;
    const float* wp1 = W + (size_t)(nb + 16 + r16) * K + kb0 + q * 8;

#pragma unroll
    for (int kk = 0; kk < KCHUNK; kk += 32) {
        short8 a0 = *(const short8*)&Xs[r16 * PITCH + kk + q * 8];
        short8 a1 = *(const short8*)&Xs[(16 + r16) * PITCH + kk + q * 8];
        {
            float4 u0 = *(const float4*)(wp0 + kk);
            float4 u1 = *(const float4*)(wp0 + kk + 4);
            short8 bf = pack8(u0, u1);
            acc[0][0] = __builtin_amdgcn_mfma_f32_16x16x32_bf16(a0, bf, acc[0][0], 0, 0, 0);
            acc[1][0] = __builtin_amdgcn_mfma_f32_16x16x32_bf16(a1, bf, acc[1][0], 0, 0, 0);
        }
        {
            float4 u0 = *(const float4*)(wp1 + kk);
            float4 u1 = *(const float4*)(wp1 + kk + 4);
            short8 bf = pack8(u0, u1);
            acc[0][1] = __builtin_amdgcn_mfma_f32_16x16x32_bf16(a0, bf, acc[0][1], 0, 0, 0);
            acc[1][1] = __builtin_amdgcn_mfma_f32_16x16x32_bf16(a1, bf, acc[1][1], 0, 0, 0);
        }
    }

    float* outp = slab + (size_t)by * 32 * N;
#pragma unroll
    for (int mt = 0; mt < 2; mt++)
#pragma unroll
        for (int nt = 0; nt < 2; nt++)
#pragma unroll
            for (int e = 0; e < 4; e++) {
                int i = mt * 16 + q * 4 + e;          // C/D: row = quad*4 + reg
                int n = nb + nt * 16 + r16;           //      col = lane&15
                outp[(size_t)i * N + n] = acc[mt][nt][e];
            }
}

// -------- chunk-sum helper: sum NCH slab partials at float4 offset -----------
template<int NCH>
__device__ inline float4 csum4(const float* __restrict__ slab, size_t stride, size_t off) {
    float4 a; a.x = 0.f; a.y = 0.f; a.z = 0.f; a.w = 0.f;
#pragma unroll 8
    for (int c = 0; c < NCH; c++) {
        const float4 v = *(const float4*)(slab + (size_t)c * stride + off);
        a.x += v.x; a.y += v.y; a.z += v.z; a.w += v.w;
    }
    return a;
}

__device__ inline float block_sum(float v, float* red, int t) {
    for (int o = 32; o; o >>= 1) v += __shfl_down(v, o);
    if ((t & 63) == 0) red[t >> 6] = v;
    __syncthreads();
    float r = red[0] + red[1] + red[2] + red[3];
    __syncthreads();
    return r;
}

#define KEXP (-9.210340371976184f / 1024.0f)   // -ln(10000)/1024

// -------- reduce(weight-gemm) + posbias -> S;  Xn = LN1(S) -------------------
__global__ __launch_bounds__(256) void rW_k(const float* __restrict__ slab,
                                            const float* __restrict__ g,
                                            const float* __restrict__ bl,
                                            float* __restrict__ S,
                                            float* __restrict__ Xn) {
    __shared__ float red[4];
    const int row = blockIdx.x, t = threadIdx.x;
    const size_t off0 = (size_t)row * 2048 + t * 4, off1 = off0 + 1024;
    float4 v0 = csum4<32>(slab, 65536, off0);
    float4 v1 = csum4<32>(slab, 65536, off1);
    const float fr = (float)row;
    const int c0 = t * 4, c1 = c0 + 1024;
    float a0 = fr * __expf((float)c0 * KEXP);
    float a1 = fr * __expf((float)(c0 + 2) * KEXP);
    float a2 = fr * __expf((float)c1 * KEXP);
    float a3 = fr * __expf((float)(c1 + 2) * KEXP);
    v0.x += sinf(a0); v0.y += cosf(a0); v0.z += sinf(a1); v0.w += cosf(a1);
    v1.x += sinf(a2); v1.y += cosf(a2); v1.z += sinf(a3); v1.w += cosf(a3);
    *(float4*)(S + off0) = v0;
    *(float4*)(S + off1) = v1;
    float s = v0.x + v0.y + v0.z + v0.w + v1.x + v1.y + v1.z + v1.w;
    float mean = block_sum(s, red, t) * (1.0f / 2048.0f);
    float d0 = v0.x - mean, d1 = v0.y - mean, d2 = v0.z - mean, d3 = v0.w - mean;
    float e0 = v1.x - mean, e1 = v1.y - mean, e2 = v1.z - mean, e3 = v1.w - mean;
    float s2 = d0*d0 + d1*d1 + d2*d2 + d3*d3 + e0*e0 + e1*e1 + e2*e2 + e3*e3;
    float var = block_sum(s2, red, t) * (1.0f / 2048.0f);
    float rs = 1.0f / sqrtf(var + 1e-5f);
    float4 g0 = *(const float4*)(g + c0), g1 = *(const float4*)(g + c1);
    float4 b0 = *(const float4*)(bl + c0), b1 = *(const float4*)(bl + c1);
    float4 o0, o1;
    o0.x = d0 * rs * g0.x + b0.x; o0.y = d1 * rs * g0.y + b0.y;
    o0.z = d2 * rs * g0.z + b0.z; o0.w = d3 * rs * g0.w + b0.w;
    o1.x = e0 * rs * g1.x + b1.x; o1.y = e1 * rs * g1.y + b1.y;
    o1.z = e2 * rs * g1.z + b1.z; o1.w = e3 * rs * g1.w + b1.w;
    *(float4*)(Xn + off0) = o0;
    *(float4*)(Xn + off1) = o1;
}

// -------- reduce(V-gemm) + inclusive cumsum over rows -> Vc ------------------
__global__ __launch_bounds__(256) void rVcum_k(const float* __restrict__ slab,
                                               float* __restrict__ Vc) {
    __shared__ float lds[32 * 64];
    const int b = blockIdx.x, t = threadIdx.x;
    {
        int row = t >> 4, c4 = t & 15;
        size_t off = (size_t)row * 2048 + b * 64 + c4 * 4;
        float4 v = csum4<32>(slab, 65536, off);
        *(float4*)&lds[row * 64 + c4 * 4] = v;
    }
    {
        int row = (t >> 4) + 16, c4 = t & 15;
        size_t off = (size_t)row * 2048 + b * 64 + c4 * 4;
        float4 v = csum4<32>(slab, 65536, off);
        *(float4*)&lds[row * 64 + c4 * 4] = v;
    }
    __syncthreads();
    if (t < 64) {
        float run = 0.f;
#pragma unroll
        for (int i = 0; i < 32; i++) {
            run += lds[i * 64 + t];
            Vc[(size_t)i * 2048 + b * 64 + t] = run;
        }
    }
}

// -------- reduce(O-gemm): Sn = sum + S_old; S2 = LN2(Sn) + Sn ----------------
__global__ __launch_bounds__(256) void rO_k(const float* __restrict__ slab,
                                            const float* __restrict__ S,
                                            const float* __restrict__ g,
                                            const float* __restrict__ bl,
                                            float* __restrict__ S2) {
    __shared__ float red[4];
    const int row = blockIdx.x, t = threadIdx.x;
    const size_t off0 = (size_t)row * 2048 + t * 4, off1 = off0 + 1024;
    float4 v0 = csum4<32>(slab, 65536, off0);
    float4 v1 = csum4<32>(slab, 65536, off1);
    const float4 s0 = *(const float4*)(S + off0);
    const float4 s1 = *(const float4*)(S + off1);
    v0.x += s0.x; v0.y += s0.y; v0.z += s0.z; v0.w += s0.w;
    v1.x += s1.x; v1.y += s1.y; v1.z += s1.z; v1.w += s1.w;
    float s = v0.x + v0.y + v0.z + v0.w + v1.x + v1.y + v1.z + v1.w;
    float mean = block_sum(s, red, t) * (1.0f / 2048.0f);
    float d0 = v0.x - mean, d1 = v0.y - mean, d2 = v0.z - mean, d3 = v0.w - mean;
    float e0 = v1.x - mean, e1 = v1.y - mean, e2 = v1.z - mean, e3 = v1.w - mean;
    float s2 = d0*d0 + d1*d1 + d2*d2 + d3*d3 + e0*e0 + e1*e1 + e2*e2 + e3*e3;
    float var = block_sum(s2, red, t) * (1.0f / 2048.0f);
    float rs = 1.0f / sqrtf(var + 1e-5f);
    const int c0 = t * 4, c1 = c0 + 1024;
    float4 g0 = *(const float4*)(g + c0), g1 = *(const float4*)(g + c1);
    float4 b0 = *(const float4*)(bl + c0), b1 = *(const float4*)(bl + c1);
    float4 o0, o1;
    o0.x = d0 * rs * g0.x + b0.x + v0.x; o0.y = d1 * rs * g0.y + b0.y + v0.y;
    o0.z = d2 * rs * g0.z + b0.z + v0.z; o0.w = d3 * rs * g0.w + b0.w + v0.w;
    o1.x = e0 * rs * g1.x + b1.x + v1.x; o1.y = e1 * rs * g1.y + b1.y + v1.y;
    o1.z = e2 * rs * g1.z + b1.z + v1.z; o1.w = e3 * rs * g1.w + b1.w + v1.w;
    *(float4*)(S2 + off0) = o0;
    *(float4*)(S2 + off1) = o1;
}

// -------- reduce(fc1-gemm) + bias + exact gelu -> Hb (32 x 8192) -------------
__global__ __launch_bounds__(256) void rFC1_k(const float* __restrict__ slab,
                                              const float* __restrict__ bias,
                                              float* __restrict__ Hb) {
    const int row = blockIdx.x, t = threadIdx.x;
#pragma unroll
    for (int j = 0; j < 8; j++) {
        const int c4 = t + 256 * j;
        const size_t off = (size_t)row * 8192 + c4 * 4;
        float4 v = csum4<8>(slab, 262144, off);
        const float4 bb = *(const float4*)(bias + c4 * 4);
        v.x += bb.x; v.y += bb.y; v.z += bb.z; v.w += bb.w;
        v.x = 0.5f * v.x * (1.0f + erff(v.x * 0.70710678118654752f));
        v.y = 0.5f * v.y * (1.0f + erff(v.y * 0.70710678118654752f));
        v.z = 0.5f * v.z * (1.0f + erff(v.z * 0.70710678118654752f));
        v.w = 0.5f * v.w * (1.0f + erff(v.w * 0.70710678118654752f));
        *(float4*)(Hb + off) = v;
    }
}

// -------- reduce(fc2-gemm) + bias -> Sdst;  Xn = LN1(Sdst) -------------------
__global__ __launch_bounds__(256) void rFC2_k(const float* __restrict__ slab,
                                              const float* __restrict__ bias,
                                              float* __restrict__ Sdst,
                                              float* __restrict__ Xn,
                                              const float* __restrict__ g,
                                              const float* __restrict__ bl) {
    __shared__ float red[4];
    const int row = blockIdx.x, t = threadIdx.x;
    const size_t off0 = (size_t)row * 2048 + t * 4, off1 = off0 + 1024;
    const int c0 = t * 4, c1 = c0 + 1024;
    float4 v0 = csum4<32>(slab, 65536, off0);
    float4 v1 = csum4<32>(slab, 65536, off1);
    const float4 bb0 = *(const float4*)(bias + c0);
    const float4 bb1 = *(const float4*)(bias + c1);
    v0.x += bb0.x; v0.y += bb0.y; v0.z += bb0.z; v0.w += bb0.w;
    v1.x += bb1.x; v1.y += bb1.y; v1.z += bb1.z; v1.w += bb1.w;
    *(float4*)(Sdst + off0) = v0;
    *(float4*)(Sdst + off1) = v1;
    float s = v0.x + v0.y + v0.z + v0.w + v1.x + v1.y + v1.z + v1.w;
    float mean = block_sum(s, red, t) * (1.0f / 2048.0f);
    float d0 = v0.x - mean, d1 = v0.y - mean, d2 = v0.z - mean, d3 = v0.w - mean;
    float e0 = v1.x - mean, e1 = v1.y - mean, e2 = v1.z - mean, e3 = v1.w - mean;
    float s2 = d0*d0 + d1*d1 + d2*d2 + d3*d3 + e0*e0 + e1*e1 + e2*e2 + e3*e3;
    float var = block_sum(s2, red, t) * (1.0f / 2048.0f);
    float rs = 1.0f / sqrtf(var + 1e-5f);
    float4 g0 = *(const float4*)(g + c0), g1 = *(const float4*)(g + c1);
    float4 b0 = *(const float4*)(bl + c0), b1 = *(const float4*)(bl + c1);
    float4 o0, o1;
    o0.x = d0 * rs * g0.x + b0.x; o0.y = d1 * rs * g0.y + b0.y;
    o0.z = d2 * rs * g0.z + b0.z; o0.w = d3 * rs * g0.w + b0.w;
    o1.x = e0 * rs * g1.x + b1.x; o1.y = e1 * rs * g1.y + b1.y;
    o1.z = e2 * rs * g1.z + b1.z; o1.w = e3 * rs * g1.w + b1.w;
    *(float4*)(Xn + off0) = o0;
    *(float4*)(Xn + off1) = o1;
}

extern "C" void kernel_launch(void* const* d_in, const int* in_sizes, int n_in,
                              void* d_out, int out_size, void* d_ws, size_t ws_size,
                              hipStream_t stream) {
    const float* x      = (const float*)d_in[0];
    const float* weight = (const float*)d_in[1];
    // d_in[2] = Wq, d_in[3] = Wk: dead (softmax over a scalar == 1)
    const float* Wv     = (const float*)d_in[4];
    const float* Wo     = (const float*)d_in[5];
    const float* ln1g   = (const float*)d_in[6];
    const float* ln1b   = (const float*)d_in[7];
    const float* ln2g   = (const float*)d_in[8];
    const float* ln2b   = (const float*)d_in[9];
    const float* fc1w   = (const float*)d_in[10];
    const float* fc1b   = (const float*)d_in[11];
    const float* fc2w   = (const float*)d_in[12];
    const float* fc2b   = (const float*)d_in[13];
    float* ws   = (float*)d_ws;
    float* xcf  = ws;                 // 32*2048
    float* S    = ws + 65536;         // 32*2048
    float* Xn   = ws + 131072;        // 32*2048
    float* S2   = ws + 196608;        // 32*2048
    float* Vc   = ws + 262144;        // 32*2048
    float* Hb   = ws + 327680;        // 32*8192
    float* slab = ws + 589824;        // 32 * 32*2048 (8 MB, shared by all GEMMs)
    float* out  = (float*)d_out;

    avg_k<<<2048, 128, 0, stream>>>(x, xcf);

    gemm_k<64><<<dim3(16, 32), 256, 0, stream>>>(xcf, weight, slab, 2048, 2048);
    rW_k<<<32, 256, 0, stream>>>(slab, ln1g, ln1b, S, Xn);

    for (int a = 0; a < 3; a++) {
        gemm_k<64><<<dim3(16, 32), 256, 0, stream>>>(Xn, Wv + (size_t)a * 4194304, slab, 2048, 2048);
        rVcum_k<<<32, 256, 0, stream>>>(slab, Vc);
        gemm_k<64><<<dim3(16, 32), 256, 0, stream>>>(Vc, Wo + (size_t)a * 4194304, slab, 2048, 2048);
        rO_k<<<32, 256, 0, stream>>>(slab, S, ln2g, ln2b, S2);
        gemm_k<256><<<dim3(64, 8), 256, 0, stream>>>(S2, fc1w, slab, 8192, 2048);
        rFC1_k<<<32, 256, 0, stream>>>(slab, fc1b, Hb);
        gemm_k<256><<<dim3(16, 32), 256, 0, stream>>>(Hb, fc2w, slab, 2048, 8192);
        rFC2_k<<<32, 256, 0, stream>>>(slab, fc2b, (a == 2) ? out : S, Xn, ln1g, ln1b);
    }
}